// Round 2
// baseline (562.179 us; speedup 1.0000x reference)
//
#include <hip/hip_runtime.h>
#include <stdint.h>

#define B_    32
#define N_    22743
#define C_    80
#define BN    (B_ * N_)          // 727776
#define TOPK_ 1000
#define CAP   16384
#define SORTN 4096

// ---------- helpers ----------

// float32 sigmoid via double internal (closest to faithfully-rounded np result)
__device__ __forceinline__ float sig32(float x) {
    return (float)(1.0 / (1.0 + exp(-(double)x)));
}

// ---------- kernels ----------

__global__ void k_init(uint32_t* hist, uint32_t* ctl) {
    int t = threadIdx.x;
    if (t < 256) hist[t] = 0;
    if (t == 0) { ctl[0] = 0; ctl[1] = TOPK_; ctl[2] = 0; ctl[3] = 0; }
}

// conf = sigmoid(p[...,4]); score = conf > 0.05 ? conf : 0 ; store raw f32 bits
__global__ void k_scores(const float* __restrict__ p, uint32_t* __restrict__ sc) {
    int i = blockIdx.x * blockDim.x + threadIdx.x;
    if (i >= BN) return;
    float x = p[(size_t)i * 85 + 4];
    float c = sig32(x);
    float s = (c > 0.05f) ? c : 0.0f;
    sc[i] = __float_as_uint(s);
}

// byte-wise radix-select histogram, round r (0 = MSB)
__global__ void k_hist(const uint32_t* __restrict__ sc, uint32_t* __restrict__ hist,
                       const uint32_t* __restrict__ ctl, int r) {
    __shared__ uint32_t sh[256];
    if (threadIdx.x < 256) sh[threadIdx.x] = 0;
    __syncthreads();
    uint32_t pref = ctl[0];
    int shPrefix = 32 - 8 * r;   // 64-bit shift below, so 32 is fine
    int shBin = 24 - 8 * r;
    uint64_t prefHi = (uint64_t)pref >> shPrefix;
    int stride = gridDim.x * blockDim.x;
    for (int i = blockIdx.x * blockDim.x + threadIdx.x; i < BN; i += stride) {
        uint32_t s = sc[i];
        if (((uint64_t)s >> shPrefix) == prefHi)
            atomicAdd(&sh[(s >> shBin) & 0xFFu], 1u);
    }
    __syncthreads();
    if (threadIdx.x < 256 && sh[threadIdx.x])
        atomicAdd(&hist[threadIdx.x], sh[threadIdx.x]);
}

__global__ void k_scan(uint32_t* hist, uint32_t* ctl, int r) {
    __shared__ uint32_t sh[256];
    int t = threadIdx.x;
    sh[t] = hist[t];
    __syncthreads();
    hist[t] = 0;                           // ready for next round
    if (t == 0) {
        uint32_t krem = ctl[1];
        uint32_t cum = 0;
        int b = 255;
        for (; b >= 0; --b) {
            uint32_t h = sh[b];
            if (cum + h >= krem) break;
            cum += h;
        }
        if (b < 0) b = 0;
        ctl[2] += cum;                     // count strictly above this bin
        ctl[1] = krem - cum;               // remaining slots inside bin
        ctl[0] |= ((uint32_t)b) << (24 - 8 * r);
    }
}

// compact all elements with score_bits >= T; key = (score<<32) | ~idx
__global__ void k_compact(const uint32_t* __restrict__ sc, uint32_t* ctl,
                          unsigned long long* __restrict__ cand) {
    uint32_t T = ctl[0];
    int stride = gridDim.x * blockDim.x;
    for (int i = blockIdx.x * blockDim.x + threadIdx.x; i < BN; i += stride) {
        uint32_t s = sc[i];
        if (s >= T) {
            uint32_t pos = atomicAdd(&ctl[3], 1u);
            if (pos < CAP)
                cand[pos] = ((unsigned long long)s << 32) | (uint32_t)(~(uint32_t)i);
        }
    }
}

// single-block bitonic sort (descending) of up to SORTN keys; emit top-1000
__global__ __launch_bounds__(1024) void k_sort(const unsigned long long* __restrict__ cand,
                                               const uint32_t* __restrict__ ctl,
                                               uint32_t* __restrict__ sel_idx,
                                               uint32_t* __restrict__ sel_sb) {
    __shared__ unsigned long long key[SORTN];
    uint32_t cnt = ctl[3];
    if (cnt > CAP) cnt = CAP;
    if (cnt > SORTN) cnt = SORTN;
    for (int t = threadIdx.x; t < SORTN; t += blockDim.x)
        key[t] = (t < (int)cnt) ? cand[t] : 0ull;
    __syncthreads();
    for (int k = 2; k <= SORTN; k <<= 1) {
        for (int j = k >> 1; j > 0; j >>= 1) {
            for (int t = threadIdx.x; t < SORTN; t += blockDim.x) {
                int ixj = t ^ j;
                if (ixj > t) {
                    unsigned long long a = key[t], b = key[ixj];
                    bool up = ((t & k) == 0);           // descending overall
                    if (up ? (a < b) : (a > b)) { key[t] = b; key[ixj] = a; }
                }
            }
            __syncthreads();
        }
    }
    for (int t = threadIdx.x; t < TOPK_; t += blockDim.x) {
        unsigned long long kk = key[t];
        sel_sb[t] = (uint32_t)(kk >> 32);
        sel_idx[t] = ~((uint32_t)kk);
    }
}

// per selected candidate: decode box, label, nms-offset box, area
// All float ops on the box path use explicit _rn intrinsics: no fp-contract,
// bit-identical to the reference's unfused float32 graph.
__global__ void k_prep(const float* __restrict__ p, const float* __restrict__ ancs,
                       const float* __restrict__ fsize,
                       const uint32_t* __restrict__ sel_idx,
                       const uint32_t* __restrict__ sel_sb,
                       float4* __restrict__ obox, float4* __restrict__ boxo,
                       float* __restrict__ area, int* __restrict__ ids,
                       int* __restrict__ labels, uint32_t* __restrict__ svalid,
                       float* __restrict__ sscore) {
    int j = blockIdx.x * blockDim.x + threadIdx.x;
    if (j >= TOPK_) return;
    uint32_t i = sel_idx[j];
    if (i >= (uint32_t)BN) i = 0;                       // safety (pad entries)
    int b = (int)(i / (uint32_t)N_);
    int n = (int)(i - (uint32_t)b * (uint32_t)N_);
    const float* row = p + (size_t)i * 85;
    float ax = ancs[n * 4 + 0], ay = ancs[n * 4 + 1];
    float aw = ancs[n * 4 + 2], ah = ancs[n * 4 + 3];
    float fx = fsize[n * 2 + 0], fy = fsize[n * 2 + 1];
    float x = __fadd_rn(ax, __fdiv_rn(sig32(row[0]), fx));
    float y = __fadd_rn(ay, __fdiv_rn(sig32(row[1]), fy));
    float w = __fmul_rn((float)exp((double)row[2]), aw);
    float h = __fmul_rn((float)exp((double)row[3]), ah);
    float hw = __fmul_rn(w, 0.5f), hh = __fmul_rn(h, 0.5f);
    float l = __fsub_rn(x, hw), t = __fsub_rn(y, hh);
    float r = __fadd_rn(x, hw), bt = __fadd_rn(y, hh);
    float best = -1.0f; int lab = 0;
    for (int c = 0; c < C_; ++c) {
        float s = sig32(row[5 + c]);
        if (s > best) { best = s; lab = c; }            // first max wins, like np.argmax
    }
    int label = lab + 1;
    float keyf = (float)(b * (C_ + 1) + label);
    float off = __fmul_rn(keyf, 10.0f);
    float4 ob = make_float4(__fadd_rn(l, off), __fadd_rn(t, off),
                            __fadd_rn(r, off), __fadd_rn(bt, off));
    obox[j] = ob;
    boxo[j] = make_float4(l, t, r, bt);
    float dx = __fsub_rn(ob.z, ob.x), dy = __fsub_rn(ob.w, ob.y);  // area of OFFSET boxes (matches ref)
    area[j] = __fmul_rn(dx, dy);
    ids[j] = b;
    labels[j] = label;
    float sc = __uint_as_float(sel_sb[j]);
    sscore[j] = sc;
    svalid[j] = (sc > 0.0f) ? 1u : 0u;
}

// suppression mask: bit (i, col) set iff col>i && iou(i,col) > 0.5
__global__ void k_mask(const float4* __restrict__ obox, const float* __restrict__ area,
                       unsigned long long* __restrict__ mask) {
    int gtid = blockIdx.x * blockDim.x + threadIdx.x;
    int wid = gtid >> 6;
    int lane = threadIdx.x & 63;
    if (wid >= TOPK_ * 16) return;
    int i = wid >> 4, c = wid & 15;
    int col = (c << 6) | lane;
    float4 bi = obox[i];
    float ai = area[i];
    bool pred = false;
    if (col < TOPK_ && col > i) {
        float4 bj = obox[col];
        float lx = fmaxf(bi.x, bj.x), ly = fmaxf(bi.y, bj.y);
        float rx = fminf(bi.z, bj.z), ry = fminf(bi.w, bj.w);
        float ww = fmaxf(__fsub_rn(rx, lx), 0.0f);
        float hh = fmaxf(__fsub_rn(ry, ly), 0.0f);
        float inter = __fmul_rn(ww, hh);
        float denom = __fadd_rn(__fsub_rn(__fadd_rn(ai, area[col]), inter), 1e-9f);
        float iou = __fdiv_rn(inter, denom);
        pred = iou > 0.5f;
    }
    unsigned long long m = __ballot(pred);
    if (lane == 0) mask[wid] = m;
}

// serial greedy pass (single wave, two 500-row LDS halves) + float32 output write
__global__ __launch_bounds__(1024) void k_nms_out(
        const unsigned long long* __restrict__ gmask,
        const uint32_t* __restrict__ svalid,
        const float4* __restrict__ boxo,
        const int* __restrict__ ids, const int* __restrict__ labels,
        const float* __restrict__ sscore,
        float* __restrict__ out) {
    __shared__ unsigned long long smask[500 * 16];      // 64000 B
    __shared__ unsigned long long srem[16];
    __shared__ unsigned char sval[TOPK_];
    int tid = threadIdx.x;
    for (int t = tid; t < TOPK_; t += 1024) sval[t] = (unsigned char)svalid[t];
    for (int t = tid; t < 8000; t += 1024) smask[t] = gmask[t];
    __syncthreads();
    unsigned long long removed = 0;
    if (tid < 64) {
        for (int i = 0; i < 500; ++i) {
            int w = i >> 6, bit = i & 63;
            unsigned long long rm_i = __shfl(removed, w);
            bool live = sval[i] && !((rm_i >> bit) & 1ull);
            if (live && tid < 16) removed |= smask[i * 16 + tid];
        }
    }
    __syncthreads();
    for (int t = tid; t < 8000; t += 1024) smask[t] = gmask[8000 + t];
    __syncthreads();
    if (tid < 64) {
        for (int i = 500; i < 1000; ++i) {
            int w = i >> 6, bit = i & 63;
            unsigned long long rm_i = __shfl(removed, w);
            bool live = sval[i] && !((rm_i >> bit) & 1ull);
            if (live && tid < 16) removed |= smask[(i - 500) * 16 + tid];
        }
        if (tid < 16) srem[tid] = removed;
    }
    __syncthreads();
    for (int j = tid; j < TOPK_; j += 1024) {
        bool keep = sval[j] && !((srem[j >> 6] >> (j & 63)) & 1ull);
        float4 bx = boxo[j];
        out[j]                = keep ? (float)ids[j] : -1.0f;
        out[1000 + 4 * j + 0] = keep ? bx.x : 0.0f;
        out[1000 + 4 * j + 1] = keep ? bx.y : 0.0f;
        out[1000 + 4 * j + 2] = keep ? bx.z : 0.0f;
        out[1000 + 4 * j + 3] = keep ? bx.w : 0.0f;
        out[5000 + j]         = keep ? (float)labels[j] : -1.0f;
        out[6000 + j]         = keep ? sscore[j] : 0.0f;
        out[7000 + j]         = keep ? 1.0f : 0.0f;
    }
}

// ---------- launch ----------

extern "C" void kernel_launch(void* const* d_in, const int* in_sizes, int n_in,
                              void* d_out, int out_size, void* d_ws, size_t ws_size,
                              hipStream_t stream) {
    const float* p     = (const float*)d_in[0];
    const float* ancs  = (const float*)d_in[1];
    const float* fsize = (const float*)d_in[2];

    char* ws = (char*)d_ws;
    size_t off = 0;
    uint32_t* sc = (uint32_t*)(ws + off);                 off += (size_t)BN * 4;   // 2,911,104
    uint32_t* hist = (uint32_t*)(ws + off);               off += 1024;
    uint32_t* ctl = (uint32_t*)(ws + off);                off += 64;
    unsigned long long* cand = (unsigned long long*)(ws + off); off += (size_t)CAP * 8;
    uint32_t* sel_idx = (uint32_t*)(ws + off);            off += 4096;
    uint32_t* sel_sb = (uint32_t*)(ws + off);             off += 4096;
    float4* obox = (float4*)(ws + off);                   off += 16 * 1024;
    float4* boxo = (float4*)(ws + off);                   off += 16 * 1024;
    float* area = (float*)(ws + off);                     off += 4096;
    int* ids = (int*)(ws + off);                          off += 4096;
    int* labels = (int*)(ws + off);                       off += 4096;
    uint32_t* svalid = (uint32_t*)(ws + off);             off += 4096;
    float* sscore = (float*)(ws + off);                   off += 4096;
    unsigned long long* mask = (unsigned long long*)(ws + off); off += 16000 * 8;

    k_init<<<1, 256, 0, stream>>>(hist, ctl);
    k_scores<<<(BN + 255) / 256, 256, 0, stream>>>(p, sc);
    for (int r = 0; r < 4; ++r) {
        k_hist<<<512, 256, 0, stream>>>(sc, hist, ctl, r);
        k_scan<<<1, 256, 0, stream>>>(hist, ctl, r);
    }
    k_compact<<<512, 256, 0, stream>>>(sc, ctl, cand);
    k_sort<<<1, 1024, 0, stream>>>(cand, ctl, sel_idx, sel_sb);
    k_prep<<<4, 256, 0, stream>>>(p, ancs, fsize, sel_idx, sel_sb,
                                  obox, boxo, area, ids, labels, svalid, sscore);
    k_mask<<<4000, 256, 0, stream>>>(obox, area, mask);
    k_nms_out<<<1, 1024, 0, stream>>>(mask, svalid, boxo, ids, labels, sscore,
                                      (float*)d_out);
}